// Round 5
// baseline (5783.865 us; speedup 1.0000x reference)
//
#include <hip/hip_runtime.h>
#include <math.h>

#define N_NODES 100000
#define N_EDGES 3200000
#define NFEAT 512
#define NHID 256
#define NCLASS 16
#define NLAYERS 8

#define SCAN_CHUNK 1024
#define NB ((N_NODES + SCAN_CHUNK - 1) / SCAN_CHUNK)   // 98

typedef float f32x4 __attribute__((ext_vector_type(4)));
typedef short s16x8 __attribute__((ext_vector_type(8)));

__device__ __forceinline__ unsigned short bf16_rne(float f) {
  unsigned u = __float_as_uint(f);
  unsigned r = 0x7fffu + ((u >> 16) & 1u);
  return (unsigned short)((u + r) >> 16);
}
__device__ __forceinline__ float bf16_tof(unsigned short h) {
  return __uint_as_float(((unsigned)h) << 16);
}

__device__ __forceinline__ void async16(void* lds_dst, const void* gsrc) {
  __builtin_amdgcn_global_load_lds(
      (const __attribute__((address_space(1))) unsigned int*)gsrc,
      (__attribute__((address_space(3))) unsigned int*)lds_dst, 16, 0, 0);
}

// ---------------- CSR build ----------------
__global__ void k_hist(const int* __restrict__ dst, int* __restrict__ cnt) {
  int i = blockIdx.x * 256 + threadIdx.x;
  if (i < N_EDGES) atomicAdd(&cnt[dst[i]], 1);
}

__global__ void k_blocksum(const int* __restrict__ cnt, int* __restrict__ bs) {
  __shared__ int red[256];
  int b = blockIdx.x, t = threadIdx.x;
  int s = 0;
  int base = b * SCAN_CHUNK;
  for (int j = 0; j < 4; ++j) {
    int i = base + t + j * 256;
    if (i < N_NODES) s += cnt[i];
  }
  red[t] = s;
  __syncthreads();
  for (int off = 128; off > 0; off >>= 1) {
    if (t < off) red[t] += red[t + off];
    __syncthreads();
  }
  if (t == 0) bs[b] = red[0];
}

__global__ void k_scan_top(int* __restrict__ bs, int* __restrict__ rp) {
  if (threadIdx.x == 0) {
    int run = 0;
    for (int b = 0; b < NB; ++b) { int v = bs[b]; bs[b] = run; run += v; }
    rp[N_NODES] = run;
  }
}

__global__ void k_scan_write(const int* __restrict__ cnt, const int* __restrict__ bs,
                             int* __restrict__ rp) {
  __shared__ int tot[256];
  int b = blockIdx.x, t = threadIdx.x;
  int base = b * SCAN_CHUNK + t * 4;
  int v0 = 0, v1 = 0, v2 = 0, v3 = 0;
  if (base + 0 < N_NODES) v0 = cnt[base + 0];
  if (base + 1 < N_NODES) v1 = cnt[base + 1];
  if (base + 2 < N_NODES) v2 = cnt[base + 2];
  if (base + 3 < N_NODES) v3 = cnt[base + 3];
  int tsum = v0 + v1 + v2 + v3;
  tot[t] = tsum;
  __syncthreads();
  for (int off = 1; off < 256; off <<= 1) {
    int v = 0;
    if (t >= off) v = tot[t - off];
    __syncthreads();
    if (t >= off) tot[t] += v;
    __syncthreads();
  }
  int excl = tot[t] - tsum + bs[b];
  if (base + 0 < N_NODES) rp[base + 0] = excl;
  if (base + 1 < N_NODES) rp[base + 1] = excl + v0;
  if (base + 2 < N_NODES) rp[base + 2] = excl + v0 + v1;
  if (base + 3 < N_NODES) rp[base + 3] = excl + v0 + v1 + v2;
}

__global__ void k_fill(const int* __restrict__ src, const int* __restrict__ dst,
                       const float* __restrict__ w, const int* __restrict__ rp,
                       int* __restrict__ fill, int* __restrict__ col,
                       float* __restrict__ val) {
  int i = blockIdx.x * 256 + threadIdx.x;
  if (i < N_EDGES) {
    int d = dst[i];
    int pos = rp[d] + atomicAdd(&fill[d], 1);
    col[pos] = src[i];
    val[pos] = w[i];
  }
}

// ---------------- SpMM + fused support, QUARTER feature split ----------------
// Round-4 counters: FETCH 786 MB/half-pass vs 126 compulsory -> L3 gather
// hit-rate ~60%; eviction by co-resident streams. Fix: quarter split
// (gather footprint 25 MB/pass, 2 cache lines per edge, same total lines
// as half-split) + nontemporal h0 load / sup store so single-use streams
// don't evict the gather set. col/val stay cacheable (reused 32x).
// Gather stays fp32 (precision: logits ~1e7 scale, in-band sign flips
// rule out bf16/fp16 gathers).
__global__ __launch_bounds__(256)
void k_spmm_q(const int* __restrict__ rp, const int* __restrict__ col,
              const float* __restrict__ val, const float* __restrict__ h,
              const float* __restrict__ h0,
              unsigned short* __restrict__ sup_hi,
              unsigned short* __restrict__ sup_lo, int f0) {
  int wave = threadIdx.x >> 6;
  int lane = threadIdx.x & 63;
  int node = blockIdx.x * 4 + wave;
  if (node >= N_NODES) return;
  int e0 = rp[node], e1 = rp[node + 1];
  int fo = f0 + lane;                       // lane owns one column

  float a0 = 0.f, a1 = 0.f, a2 = 0.f, a3 = 0.f;

  int e = e0;
  for (; e + 4 <= e1; e += 4) {
    int s0 = col[e], s1 = col[e + 1], s2 = col[e + 2], s3 = col[e + 3];
    float w0 = val[e], w1 = val[e + 1], w2 = val[e + 2], w3 = val[e + 3];
    float v0 = h[(size_t)s0 * 256 + fo];    // 64 lanes x 4B = 256B = 2 lines
    float v1 = h[(size_t)s1 * 256 + fo];
    float v2 = h[(size_t)s2 * 256 + fo];
    float v3 = h[(size_t)s3 * 256 + fo];
    a0 += w0 * v0;
    a1 += w1 * v1;
    a2 += w2 * v2;
    a3 += w3 * v3;
  }
  for (; e < e1; ++e) {
    a0 += val[e] * h[(size_t)col[e] * 256 + fo];
  }

  float acc = (a0 + a1) + (a2 + a3);
  float z = __builtin_nontemporal_load(&h0[(size_t)node * 256 + fo]);
  float o = 0.9f * acc + 0.1f * z;
  unsigned short hh = bf16_rne(o);
  unsigned short ll = bf16_rne(o - bf16_tof(hh));
  __builtin_nontemporal_store(hh, &sup_hi[(size_t)node * 256 + fo]);
  __builtin_nontemporal_store(ll, &sup_lo[(size_t)node * 256 + fo]);
}

// ---------------- W split: fp32 [K][256] -> bf16 hi/lo transposed [256][K] ---
__global__ void k_splitw(const float* __restrict__ W, unsigned short* __restrict__ hi,
                         unsigned short* __restrict__ lo, int K) {
  int mat = blockIdx.y;
  const float* Wm = W + (size_t)mat * K * NHID;
  unsigned short* hm = hi + (size_t)mat * K * NHID;
  unsigned short* lm = lo + (size_t)mat * K * NHID;
  int idx = blockIdx.x * 256 + threadIdx.x;
  if (idx >= K * NHID) return;
  int k = idx >> 8;          // NHID == 256
  int n = idx & 255;
  float f = Wm[idx];
  unsigned short h = bf16_rne(f);
  unsigned short l = bf16_rne(f - bf16_tof(h));
  hm[(size_t)n * K + k] = h;
  lm[(size_t)n * K + k] = l;
}

// ---------------- MFMA GEMM, 128x256 tile, BK=32, double-buffered -----------
// (unchanged from round 4 — fragment-ordered LDS, async dbuf staging,
// coalesced LDS-transpose epilogue)
// MODE 0: out1 = out2 = relu(A@W + bias)                  (A = x,   K = 512)
// MODE 1: out1 = relu(theta*(A@W) + (1-theta)*s + hin), s = hi+lo (K = 256)
template <int MODE>
__global__ __launch_bounds__(512)
void k_gemm2(const float* __restrict__ Af,
             const unsigned short* __restrict__ Ah_g,
             const unsigned short* __restrict__ Al_g,
             const unsigned short* __restrict__ Bh_g,
             const unsigned short* __restrict__ Bl_g, int K,
             const float* __restrict__ bias, const float* __restrict__ hin,
             float* __restrict__ out1, float* __restrict__ out2, float theta) {
  __shared__ unsigned short pool[49152];   // 96 KB
  const int tid = threadIdx.x;
  const int lane = tid & 63, w = tid >> 6;
  const int wr = w >> 2, wc = w & 3;
  const int l16 = lane & 15, lk = lane >> 4;
  const int bm = blockIdx.x * 128;

  f32x4 acc[4][4];
#pragma unroll
  for (int i = 0; i < 4; ++i)
#pragma unroll
    for (int j = 0; j < 4; ++j)
#pragma unroll
      for (int q = 0; q < 4; ++q) acc[i][j][q] = 0.f;

  auto stageB = [&](int buf, int kc) {
#pragma unroll
    for (int u = 0; u < 2; ++u) {
      int fb = w * 2 + u;
      size_t go = (size_t)(fb * 16 + l16) * K + kc + lk * 8;
      async16(&pool[16384 + buf * 8192 + fb * 512], &Bh_g[go]);
      async16(&pool[32768 + buf * 8192 + fb * 512], &Bl_g[go]);
    }
  };
  auto stageA1 = [&](int buf, int kc) {
    size_t go = (size_t)(bm + w * 16 + l16) * K + kc + lk * 8;
    async16(&pool[0 + buf * 4096 + w * 512], &Ah_g[go]);
    async16(&pool[8192 + buf * 4096 + w * 512], &Al_g[go]);
  };
  float4 fa0, fa1;
  auto stageA0_issue = [&](int kc) {
    int m0 = tid >> 3, k00 = (tid & 7) * 4;
    int m1 = (tid + 512) >> 3, k01 = ((tid + 512) & 7) * 4;
    fa0 = make_float4(0.f, 0.f, 0.f, 0.f);
    fa1 = fa0;
    if (bm + m0 < N_NODES) fa0 = *(const float4*)&Af[(size_t)(bm + m0) * K + kc + k00];
    if (bm + m1 < N_NODES) fa1 = *(const float4*)&Af[(size_t)(bm + m1) * K + kc + k01];
  };
  auto stageA0_write = [&](int buf) {
#pragma unroll
    for (int p = 0; p < 2; ++p) {
      int f = tid + p * 512;
      int m = f >> 3, k0 = (f & 7) * 4;
      float4 fv = p ? fa1 : fa0;
      int L = (m >> 4) * 64 + (m & 15) + (k0 >> 3) * 16;
      unsigned short h0 = bf16_rne(fv.x), h1 = bf16_rne(fv.y);
      unsigned short h2 = bf16_rne(fv.z), h3 = bf16_rne(fv.w);
      ushort4 hv = make_ushort4(h0, h1, h2, h3);
      ushort4 lv = make_ushort4(bf16_rne(fv.x - bf16_tof(h0)),
                                bf16_rne(fv.y - bf16_tof(h1)),
                                bf16_rne(fv.z - bf16_tof(h2)),
                                bf16_rne(fv.w - bf16_tof(h3)));
      *(ushort4*)&pool[0 + buf * 4096 + L * 8 + (k0 & 7)] = hv;
      *(ushort4*)&pool[8192 + buf * 4096 + L * 8 + (k0 & 7)] = lv;
    }
  };

  if (MODE == 0) { stageA0_issue(0); stageA0_write(0); }
  else stageA1(0, 0);
  stageB(0, 0);
  __syncthreads();

  const int nt = K / 32;
  int buf = 0;
  for (int t = 0; t < nt; ++t) {
    const bool pf = (t + 1 < nt);
    if (pf) {
      if (MODE == 0) stageA0_issue((t + 1) * 32);
      else stageA1(buf ^ 1, (t + 1) * 32);
      stageB(buf ^ 1, (t + 1) * 32);
    }
    s16x8 ah[4], al[4], bh[4], bl[4];
#pragma unroll
    for (int i = 0; i < 4; ++i) {
      int fb = wr * 4 + i;
      ah[i] = *(const s16x8*)&pool[0 + buf * 4096 + fb * 512 + lane * 8];
      al[i] = *(const s16x8*)&pool[8192 + buf * 4096 + fb * 512 + lane * 8];
    }
#pragma unroll
    for (int j = 0; j < 4; ++j) {
      int fb = wc * 4 + j;
      bh[j] = *(const s16x8*)&pool[16384 + buf * 8192 + fb * 512 + lane * 8];
      bl[j] = *(const s16x8*)&pool[32768 + buf * 8192 + fb * 512 + lane * 8];
    }
#pragma unroll
    for (int i = 0; i < 4; ++i)
#pragma unroll
      for (int j = 0; j < 4; ++j)
        acc[i][j] = __builtin_amdgcn_mfma_f32_16x16x32_bf16(ah[i], bh[j], acc[i][j], 0, 0, 0);
#pragma unroll
    for (int i = 0; i < 4; ++i)
#pragma unroll
      for (int j = 0; j < 4; ++j)
        acc[i][j] = __builtin_amdgcn_mfma_f32_16x16x32_bf16(ah[i], bl[j], acc[i][j], 0, 0, 0);
#pragma unroll
    for (int i = 0; i < 4; ++i)
#pragma unroll
      for (int j = 0; j < 4; ++j)
        acc[i][j] = __builtin_amdgcn_mfma_f32_16x16x32_bf16(al[i], bh[j], acc[i][j], 0, 0, 0);
    if (MODE == 0 && pf) stageA0_write(buf ^ 1);
    __syncthreads();
    buf ^= 1;
  }

  // ---- epilogue: LDS transpose in 4 chunks of 32 rows ----
  float* Cst = (float*)pool;              // [32][260] fp32 = 33280 B
  const float omt = 1.f - theta;
  for (int g = 0; g < 4; ++g) {
    if (wr == (g >> 1)) {
#pragma unroll
      for (int ii = 0; ii < 2; ++ii) {
        int i = (g & 1) * 2 + ii;
#pragma unroll
        for (int j = 0; j < 4; ++j) {
          int colc = wc * 64 + j * 16 + l16;
#pragma unroll
          for (int q = 0; q < 4; ++q) {
            int lr = ii * 16 + lk * 4 + q;
            Cst[lr * 260 + colc] = acc[i][j][q];
          }
        }
      }
    }
    __syncthreads();
#pragma unroll
    for (int p = 0; p < 4; ++p) {
      int f = tid + p * 512;              // 0..2047
      int row = f >> 6, c4 = (f & 63) * 4;
      int gm = bm + g * 32 + row;
      if (gm < N_NODES) {
        float4 v = *(const float4*)&Cst[row * 260 + c4];
        size_t r = (size_t)gm * NHID + c4;
        float4 o;
        if (MODE == 0) {
          float4 bb = *(const float4*)&bias[c4];
          o.x = fmaxf(v.x + bb.x, 0.f);
          o.y = fmaxf(v.y + bb.y, 0.f);
          o.z = fmaxf(v.z + bb.z, 0.f);
          o.w = fmaxf(v.w + bb.w, 0.f);
          *(float4*)&out1[r] = o;
          *(float4*)&out2[r] = o;
        } else {
          ushort4 sh = *(const ushort4*)&Ah_g[r];   // K == NHID in MODE 1
          ushort4 sl = *(const ushort4*)&Al_g[r];
          float4 hv = *(const float4*)&hin[r];
          float sx = bf16_tof(sh.x) + bf16_tof(sl.x);
          float sy = bf16_tof(sh.y) + bf16_tof(sl.y);
          float sz = bf16_tof(sh.z) + bf16_tof(sl.z);
          float sw = bf16_tof(sh.w) + bf16_tof(sl.w);
          o.x = fmaxf(theta * v.x + omt * sx + hv.x, 0.f);
          o.y = fmaxf(theta * v.y + omt * sy + hv.y, 0.f);
          o.z = fmaxf(theta * v.z + omt * sz + hv.z, 0.f);
          o.w = fmaxf(theta * v.w + omt * sw + hv.w, 0.f);
          *(float4*)&out1[r] = o;
        }
      }
    }
    __syncthreads();
  }
}

// ---------------- head: out = sigmoid(h @ w1 + b1) ----------------
__global__ __launch_bounds__(256)
void k_final(const float* __restrict__ h, const float* __restrict__ w1,
             const float* __restrict__ b1, float* __restrict__ out) {
  __shared__ float ws[NHID * NCLASS];
  int t = threadIdx.x;
  for (int i = t; i < NHID * NCLASS; i += 256) ws[i] = w1[i];
  __syncthreads();
  int node = blockIdx.x * 16 + (t >> 4);
  int c = t & 15;
  if (node >= N_NODES) return;
  float acc = b1[c];
  const float* hr = &h[(size_t)node * NHID];
  for (int k = 0; k < NHID; k += 4) {
    float4 hv = *(const float4*)&hr[k];
    acc += hv.x * ws[(k + 0) * NCLASS + c];
    acc += hv.y * ws[(k + 1) * NCLASS + c];
    acc += hv.z * ws[(k + 2) * NCLASS + c];
    acc += hv.w * ws[(k + 3) * NCLASS + c];
  }
  out[(size_t)node * NCLASS + c] = 1.f / (1.f + __expf(-acc));
}

// ---------------- host ----------------
extern "C" void kernel_launch(void* const* d_in, const int* in_sizes, int n_in,
                              void* d_out, int out_size, void* d_ws, size_t ws_size,
                              hipStream_t stream) {
  const float* x        = (const float*)d_in[0];
  const int*   edge_src = (const int*)d_in[1];
  const int*   edge_dst = (const int*)d_in[2];
  const float* edge_w   = (const float*)d_in[3];
  const float* w0       = (const float*)d_in[4];
  const float* b0       = (const float*)d_in[5];
  const float* conv_w   = (const float*)d_in[6];
  const float* w1       = (const float*)d_in[7];
  const float* b1       = (const float*)d_in[8];
  float* out = (float*)d_out;

  char* ws = (char*)d_ws;
  size_t off = 0;
  auto alloc = [&](size_t bytes) {
    size_t o = off;
    off = (off + bytes + 255) & ~(size_t)255;
    return (void*)(ws + o);
  };
  float* h    = (float*)alloc((size_t)N_NODES * NHID * 4);
  float* h0   = (float*)alloc((size_t)N_NODES * NHID * 4);
  unsigned short* sup_hi = (unsigned short*)alloc((size_t)N_NODES * NHID * 2);
  unsigned short* sup_lo = (unsigned short*)alloc((size_t)N_NODES * NHID * 2);
  int*   col = (int*)alloc((size_t)N_EDGES * 4);
  float* val = (float*)alloc((size_t)N_EDGES * 4);
  int*   rp  = (int*)alloc((size_t)(N_NODES + 1) * 4);
  int*   cnt = (int*)alloc((size_t)N_NODES * 4);
  int*   bs  = (int*)alloc((size_t)NB * 4);
  unsigned short* w0t_hi = (unsigned short*)alloc((size_t)NFEAT * NHID * 2);
  unsigned short* w0t_lo = (unsigned short*)alloc((size_t)NFEAT * NHID * 2);
  unsigned short* cwt_hi = (unsigned short*)alloc((size_t)NLAYERS * NHID * NHID * 2);
  unsigned short* cwt_lo = (unsigned short*)alloc((size_t)NLAYERS * NHID * NHID * 2);
  (void)ws_size;

  // ---- CSR build ----
  (void)hipMemsetAsync(cnt, 0, (size_t)N_NODES * 4, stream);
  k_hist<<<(N_EDGES + 255) / 256, 256, 0, stream>>>(edge_dst, cnt);
  k_blocksum<<<NB, 256, 0, stream>>>(cnt, bs);
  k_scan_top<<<1, 64, 0, stream>>>(bs, rp);
  k_scan_write<<<NB, 256, 0, stream>>>(cnt, bs, rp);
  (void)hipMemsetAsync(cnt, 0, (size_t)N_NODES * 4, stream);
  k_fill<<<(N_EDGES + 255) / 256, 256, 0, stream>>>(edge_src, edge_dst, edge_w, rp,
                                                    cnt, col, val);

  // ---- split + transpose weights to bf16 hi/lo [N][K] ----
  k_splitw<<<dim3((NFEAT * NHID + 255) / 256, 1), 256, 0, stream>>>(w0, w0t_hi, w0t_lo, NFEAT);
  k_splitw<<<dim3((NHID * NHID + 255) / 256, NLAYERS), 256, 0, stream>>>(conv_w, cwt_hi, cwt_lo, NHID);

  // ---- h = relu(x@w0 + b0); h0 = h ----
  int gblocks = (N_NODES + 127) / 128;   // 782
  k_gemm2<0><<<gblocks, 512, 0, stream>>>(x, nullptr, nullptr, w0t_hi, w0t_lo,
                                          NFEAT, b0, nullptr, h, h0, 0.f);

  // ---- 8 GCNII layers ----
  for (int i = 0; i < NLAYERS; ++i) {
    float theta = logf(0.5f / (float)(i + 1) + 1.0f);
    for (int f0 = 0; f0 < NHID; f0 += 64) {
      k_spmm_q<<<(N_NODES + 3) / 4, 256, 0, stream>>>(rp, col, val, h, h0,
                                                      sup_hi, sup_lo, f0);
    }
    const unsigned short* whi = cwt_hi + (size_t)i * NHID * NHID;
    const unsigned short* wlo = cwt_lo + (size_t)i * NHID * NHID;
    k_gemm2<1><<<gblocks, 512, 0, stream>>>(nullptr, sup_hi, sup_lo, whi, wlo,
                                            NHID, nullptr, h, h, nullptr, theta);
  }

  // ---- head ----
  k_final<<<(N_NODES + 15) / 16, 256, 0, stream>>>(h, w1, b1, out);
}

// Round 6
// 5439.560 us; speedup vs baseline: 1.0633x; 1.0633x over previous
//
#include <hip/hip_runtime.h>
#include <math.h>

#define N_NODES 100000
#define N_EDGES 3200000
#define NFEAT 512
#define NHID 256
#define NCLASS 16
#define NLAYERS 8

#define SCAN_CHUNK 1024
#define NB ((N_NODES + SCAN_CHUNK - 1) / SCAN_CHUNK)   // 98

typedef float f32x4 __attribute__((ext_vector_type(4)));
typedef short s16x8 __attribute__((ext_vector_type(8)));

__device__ __forceinline__ unsigned short bf16_rne(float f) {
  unsigned u = __float_as_uint(f);
  unsigned r = 0x7fffu + ((u >> 16) & 1u);
  return (unsigned short)((u + r) >> 16);
}
__device__ __forceinline__ float bf16_tof(unsigned short h) {
  return __uint_as_float(((unsigned)h) << 16);
}

__device__ __forceinline__ void async16(void* lds_dst, const void* gsrc) {
  __builtin_amdgcn_global_load_lds(
      (const __attribute__((address_space(1))) unsigned int*)gsrc,
      (__attribute__((address_space(3))) unsigned int*)lds_dst, 16, 0, 0);
}

// ---------------- CSR build ----------------
__global__ void k_hist(const int* __restrict__ dst, int* __restrict__ cnt) {
  int i = blockIdx.x * 256 + threadIdx.x;
  if (i < N_EDGES) atomicAdd(&cnt[dst[i]], 1);
}

__global__ void k_blocksum(const int* __restrict__ cnt, int* __restrict__ bs) {
  __shared__ int red[256];
  int b = blockIdx.x, t = threadIdx.x;
  int s = 0;
  int base = b * SCAN_CHUNK;
  for (int j = 0; j < 4; ++j) {
    int i = base + t + j * 256;
    if (i < N_NODES) s += cnt[i];
  }
  red[t] = s;
  __syncthreads();
  for (int off = 128; off > 0; off >>= 1) {
    if (t < off) red[t] += red[t + off];
    __syncthreads();
  }
  if (t == 0) bs[b] = red[0];
}

__global__ void k_scan_top(int* __restrict__ bs, int* __restrict__ rp) {
  if (threadIdx.x == 0) {
    int run = 0;
    for (int b = 0; b < NB; ++b) { int v = bs[b]; bs[b] = run; run += v; }
    rp[N_NODES] = run;
  }
}

__global__ void k_scan_write(const int* __restrict__ cnt, const int* __restrict__ bs,
                             int* __restrict__ rp) {
  __shared__ int tot[256];
  int b = blockIdx.x, t = threadIdx.x;
  int base = b * SCAN_CHUNK + t * 4;
  int v0 = 0, v1 = 0, v2 = 0, v3 = 0;
  if (base + 0 < N_NODES) v0 = cnt[base + 0];
  if (base + 1 < N_NODES) v1 = cnt[base + 1];
  if (base + 2 < N_NODES) v2 = cnt[base + 2];
  if (base + 3 < N_NODES) v3 = cnt[base + 3];
  int tsum = v0 + v1 + v2 + v3;
  tot[t] = tsum;
  __syncthreads();
  for (int off = 1; off < 256; off <<= 1) {
    int v = 0;
    if (t >= off) v = tot[t - off];
    __syncthreads();
    if (t >= off) tot[t] += v;
    __syncthreads();
  }
  int excl = tot[t] - tsum + bs[b];
  if (base + 0 < N_NODES) rp[base + 0] = excl;
  if (base + 1 < N_NODES) rp[base + 1] = excl + v0;
  if (base + 2 < N_NODES) rp[base + 2] = excl + v0 + v1;
  if (base + 3 < N_NODES) rp[base + 3] = excl + v0 + v1 + v2;
}

// Single int2 scatter store per edge: round-5 counters showed the two
// separate 4B stores (col/val) dirtied 294 MB of lines for a 25.6 MB
// payload. One 8B store halves dirtied lines; also merges the SpMM's
// two read streams into one.
__global__ void k_fill(const int* __restrict__ src, const int* __restrict__ dst,
                       const float* __restrict__ w, const int* __restrict__ rp,
                       int* __restrict__ fill, int2* __restrict__ cv) {
  int i = blockIdx.x * 256 + threadIdx.x;
  if (i < N_EDGES) {
    int d = dst[i];
    int pos = rp[d] + atomicAdd(&fill[d], 1);
    cv[pos] = make_int2(src[i], __float_as_int(w[i]));
  }
}

// ---------------- SpMM variants (within-bench A/B) ----------------
// HALF split (odd layers): lane owns float2, footprint 51 MB/pass, 2 passes.
// QUARTER split (even layers): lane owns 1 float, footprint 25 MB/pass,
// 4 passes. Both: cv int2 stream, unroll-8 (8 independent gathers in
// flight per lane), NO nontemporal hints (round-5 NT poisoned L3
// residency of sup/h0). Counters disambiguate footprint-vs-width theory.
__global__ __launch_bounds__(256)
void k_spmm_h(const int* __restrict__ rp, const int2* __restrict__ cv,
              const float* __restrict__ h, const float* __restrict__ h0,
              unsigned short* __restrict__ sup_hi,
              unsigned short* __restrict__ sup_lo, int f0) {
  int wave = threadIdx.x >> 6;
  int lane = threadIdx.x & 63;
  int node = blockIdx.x * 4 + wave;
  if (node >= N_NODES) return;
  int e0 = rp[node], e1 = rp[node + 1];
  const float2* __restrict__ hv = (const float2*)h;  // row stride 128 float2
  int fo = (f0 >> 1) + lane;

  float2 a0 = make_float2(0.f, 0.f), a1 = a0, a2 = a0, a3 = a0;
  float2 a4 = a0, a5 = a0, a6 = a0, a7 = a0;

  int e = e0;
  for (; e + 8 <= e1; e += 8) {
    int2 c0 = cv[e + 0], c1 = cv[e + 1], c2 = cv[e + 2], c3 = cv[e + 3];
    int2 c4 = cv[e + 4], c5 = cv[e + 5], c6 = cv[e + 6], c7 = cv[e + 7];
    float2 v0 = hv[(size_t)c0.x * 128 + fo];
    float2 v1 = hv[(size_t)c1.x * 128 + fo];
    float2 v2 = hv[(size_t)c2.x * 128 + fo];
    float2 v3 = hv[(size_t)c3.x * 128 + fo];
    float2 v4 = hv[(size_t)c4.x * 128 + fo];
    float2 v5 = hv[(size_t)c5.x * 128 + fo];
    float2 v6 = hv[(size_t)c6.x * 128 + fo];
    float2 v7 = hv[(size_t)c7.x * 128 + fo];
    float w0 = __int_as_float(c0.y), w1 = __int_as_float(c1.y);
    float w2 = __int_as_float(c2.y), w3 = __int_as_float(c3.y);
    float w4 = __int_as_float(c4.y), w5 = __int_as_float(c5.y);
    float w6 = __int_as_float(c6.y), w7 = __int_as_float(c7.y);
    a0.x += w0 * v0.x; a0.y += w0 * v0.y;
    a1.x += w1 * v1.x; a1.y += w1 * v1.y;
    a2.x += w2 * v2.x; a2.y += w2 * v2.y;
    a3.x += w3 * v3.x; a3.y += w3 * v3.y;
    a4.x += w4 * v4.x; a4.y += w4 * v4.y;
    a5.x += w5 * v5.x; a5.y += w5 * v5.y;
    a6.x += w6 * v6.x; a6.y += w6 * v6.y;
    a7.x += w7 * v7.x; a7.y += w7 * v7.y;
  }
  for (; e < e1; ++e) {
    int2 c = cv[e];
    float w = __int_as_float(c.y);
    float2 v = hv[(size_t)c.x * 128 + fo];
    a0.x += w * v.x; a0.y += w * v.y;
  }

  float2 acc;
  acc.x = ((a0.x + a1.x) + (a2.x + a3.x)) + ((a4.x + a5.x) + (a6.x + a7.x));
  acc.y = ((a0.y + a1.y) + (a2.y + a3.y)) + ((a4.y + a5.y) + (a6.y + a7.y));

  float2 z = ((const float2*)h0)[(size_t)node * 128 + fo];
  float ox = 0.9f * acc.x + 0.1f * z.x;
  float oy = 0.9f * acc.y + 0.1f * z.y;
  unsigned short hx = bf16_rne(ox), hy = bf16_rne(oy);
  unsigned short lx = bf16_rne(ox - bf16_tof(hx));
  unsigned short ly = bf16_rne(oy - bf16_tof(hy));
  ((ushort2*)sup_hi)[(size_t)node * 128 + fo] = make_ushort2(hx, hy);
  ((ushort2*)sup_lo)[(size_t)node * 128 + fo] = make_ushort2(lx, ly);
}

__global__ __launch_bounds__(256)
void k_spmm_q(const int* __restrict__ rp, const int2* __restrict__ cv,
              const float* __restrict__ h, const float* __restrict__ h0,
              unsigned short* __restrict__ sup_hi,
              unsigned short* __restrict__ sup_lo, int f0) {
  int wave = threadIdx.x >> 6;
  int lane = threadIdx.x & 63;
  int node = blockIdx.x * 4 + wave;
  if (node >= N_NODES) return;
  int e0 = rp[node], e1 = rp[node + 1];
  int fo = f0 + lane;

  float a0 = 0.f, a1 = 0.f, a2 = 0.f, a3 = 0.f;
  float a4 = 0.f, a5 = 0.f, a6 = 0.f, a7 = 0.f;

  int e = e0;
  for (; e + 8 <= e1; e += 8) {
    int2 c0 = cv[e + 0], c1 = cv[e + 1], c2 = cv[e + 2], c3 = cv[e + 3];
    int2 c4 = cv[e + 4], c5 = cv[e + 5], c6 = cv[e + 6], c7 = cv[e + 7];
    float v0 = h[(size_t)c0.x * 256 + fo];
    float v1 = h[(size_t)c1.x * 256 + fo];
    float v2 = h[(size_t)c2.x * 256 + fo];
    float v3 = h[(size_t)c3.x * 256 + fo];
    float v4 = h[(size_t)c4.x * 256 + fo];
    float v5 = h[(size_t)c5.x * 256 + fo];
    float v6 = h[(size_t)c6.x * 256 + fo];
    float v7 = h[(size_t)c7.x * 256 + fo];
    a0 += __int_as_float(c0.y) * v0;
    a1 += __int_as_float(c1.y) * v1;
    a2 += __int_as_float(c2.y) * v2;
    a3 += __int_as_float(c3.y) * v3;
    a4 += __int_as_float(c4.y) * v4;
    a5 += __int_as_float(c5.y) * v5;
    a6 += __int_as_float(c6.y) * v6;
    a7 += __int_as_float(c7.y) * v7;
  }
  for (; e < e1; ++e) {
    int2 c = cv[e];
    a0 += __int_as_float(c.y) * h[(size_t)c.x * 256 + fo];
  }

  float acc = ((a0 + a1) + (a2 + a3)) + ((a4 + a5) + (a6 + a7));
  float z = h0[(size_t)node * 256 + fo];
  float o = 0.9f * acc + 0.1f * z;
  unsigned short hh = bf16_rne(o);
  unsigned short ll = bf16_rne(o - bf16_tof(hh));
  sup_hi[(size_t)node * 256 + fo] = hh;
  sup_lo[(size_t)node * 256 + fo] = ll;
}

// ---------------- W split: fp32 [K][256] -> bf16 hi/lo transposed [256][K] ---
__global__ void k_splitw(const float* __restrict__ W, unsigned short* __restrict__ hi,
                         unsigned short* __restrict__ lo, int K) {
  int mat = blockIdx.y;
  const float* Wm = W + (size_t)mat * K * NHID;
  unsigned short* hm = hi + (size_t)mat * K * NHID;
  unsigned short* lm = lo + (size_t)mat * K * NHID;
  int idx = blockIdx.x * 256 + threadIdx.x;
  if (idx >= K * NHID) return;
  int k = idx >> 8;          // NHID == 256
  int n = idx & 255;
  float f = Wm[idx];
  unsigned short h = bf16_rne(f);
  unsigned short l = bf16_rne(f - bf16_tof(h));
  hm[(size_t)n * K + k] = h;
  lm[(size_t)n * K + k] = l;
}

// ---------------- MFMA GEMM, 128x256 tile, BK=32, double-buffered -----------
// (unchanged from round 4 — fragment-ordered LDS, async dbuf staging,
// coalesced LDS-transpose epilogue)
// MODE 0: out1 = out2 = relu(A@W + bias)                  (A = x,   K = 512)
// MODE 1: out1 = relu(theta*(A@W) + (1-theta)*s + hin), s = hi+lo (K = 256)
template <int MODE>
__global__ __launch_bounds__(512)
void k_gemm2(const float* __restrict__ Af,
             const unsigned short* __restrict__ Ah_g,
             const unsigned short* __restrict__ Al_g,
             const unsigned short* __restrict__ Bh_g,
             const unsigned short* __restrict__ Bl_g, int K,
             const float* __restrict__ bias, const float* __restrict__ hin,
             float* __restrict__ out1, float* __restrict__ out2, float theta) {
  __shared__ unsigned short pool[49152];   // 96 KB
  const int tid = threadIdx.x;
  const int lane = tid & 63, w = tid >> 6;
  const int wr = w >> 2, wc = w & 3;
  const int l16 = lane & 15, lk = lane >> 4;
  const int bm = blockIdx.x * 128;

  f32x4 acc[4][4];
#pragma unroll
  for (int i = 0; i < 4; ++i)
#pragma unroll
    for (int j = 0; j < 4; ++j)
#pragma unroll
      for (int q = 0; q < 4; ++q) acc[i][j][q] = 0.f;

  auto stageB = [&](int buf, int kc) {
#pragma unroll
    for (int u = 0; u < 2; ++u) {
      int fb = w * 2 + u;
      size_t go = (size_t)(fb * 16 + l16) * K + kc + lk * 8;
      async16(&pool[16384 + buf * 8192 + fb * 512], &Bh_g[go]);
      async16(&pool[32768 + buf * 8192 + fb * 512], &Bl_g[go]);
    }
  };
  auto stageA1 = [&](int buf, int kc) {
    size_t go = (size_t)(bm + w * 16 + l16) * K + kc + lk * 8;
    async16(&pool[0 + buf * 4096 + w * 512], &Ah_g[go]);
    async16(&pool[8192 + buf * 4096 + w * 512], &Al_g[go]);
  };
  float4 fa0, fa1;
  auto stageA0_issue = [&](int kc) {
    int m0 = tid >> 3, k00 = (tid & 7) * 4;
    int m1 = (tid + 512) >> 3, k01 = ((tid + 512) & 7) * 4;
    fa0 = make_float4(0.f, 0.f, 0.f, 0.f);
    fa1 = fa0;
    if (bm + m0 < N_NODES) fa0 = *(const float4*)&Af[(size_t)(bm + m0) * K + kc + k00];
    if (bm + m1 < N_NODES) fa1 = *(const float4*)&Af[(size_t)(bm + m1) * K + kc + k01];
  };
  auto stageA0_write = [&](int buf) {
#pragma unroll
    for (int p = 0; p < 2; ++p) {
      int f = tid + p * 512;
      int m = f >> 3, k0 = (f & 7) * 4;
      float4 fv = p ? fa1 : fa0;
      int L = (m >> 4) * 64 + (m & 15) + (k0 >> 3) * 16;
      unsigned short h0 = bf16_rne(fv.x), h1 = bf16_rne(fv.y);
      unsigned short h2 = bf16_rne(fv.z), h3 = bf16_rne(fv.w);
      ushort4 hv = make_ushort4(h0, h1, h2, h3);
      ushort4 lv = make_ushort4(bf16_rne(fv.x - bf16_tof(h0)),
                                bf16_rne(fv.y - bf16_tof(h1)),
                                bf16_rne(fv.z - bf16_tof(h2)),
                                bf16_rne(fv.w - bf16_tof(h3)));
      *(ushort4*)&pool[0 + buf * 4096 + L * 8 + (k0 & 7)] = hv;
      *(ushort4*)&pool[8192 + buf * 4096 + L * 8 + (k0 & 7)] = lv;
    }
  };

  if (MODE == 0) { stageA0_issue(0); stageA0_write(0); }
  else stageA1(0, 0);
  stageB(0, 0);
  __syncthreads();

  const int nt = K / 32;
  int buf = 0;
  for (int t = 0; t < nt; ++t) {
    const bool pf = (t + 1 < nt);
    if (pf) {
      if (MODE == 0) stageA0_issue((t + 1) * 32);
      else stageA1(buf ^ 1, (t + 1) * 32);
      stageB(buf ^ 1, (t + 1) * 32);
    }
    s16x8 ah[4], al[4], bh[4], bl[4];
#pragma unroll
    for (int i = 0; i < 4; ++i) {
      int fb = wr * 4 + i;
      ah[i] = *(const s16x8*)&pool[0 + buf * 4096 + fb * 512 + lane * 8];
      al[i] = *(const s16x8*)&pool[8192 + buf * 4096 + fb * 512 + lane * 8];
    }
#pragma unroll
    for (int j = 0; j < 4; ++j) {
      int fb = wc * 4 + j;
      bh[j] = *(const s16x8*)&pool[16384 + buf * 8192 + fb * 512 + lane * 8];
      bl[j] = *(const s16x8*)&pool[32768 + buf * 8192 + fb * 512 + lane * 8];
    }
#pragma unroll
    for (int i = 0; i < 4; ++i)
#pragma unroll
      for (int j = 0; j < 4; ++j)
        acc[i][j] = __builtin_amdgcn_mfma_f32_16x16x32_bf16(ah[i], bh[j], acc[i][j], 0, 0, 0);
#pragma unroll
    for (int i = 0; i < 4; ++i)
#pragma unroll
      for (int j = 0; j < 4; ++j)
        acc[i][j] = __builtin_amdgcn_mfma_f32_16x16x32_bf16(ah[i], bl[j], acc[i][j], 0, 0, 0);
#pragma unroll
    for (int i = 0; i < 4; ++i)
#pragma unroll
      for (int j = 0; j < 4; ++j)
        acc[i][j] = __builtin_amdgcn_mfma_f32_16x16x32_bf16(al[i], bh[j], acc[i][j], 0, 0, 0);
    if (MODE == 0 && pf) stageA0_write(buf ^ 1);
    __syncthreads();
    buf ^= 1;
  }

  // ---- epilogue: LDS transpose in 4 chunks of 32 rows ----
  float* Cst = (float*)pool;              // [32][260] fp32 = 33280 B
  const float omt = 1.f - theta;
  for (int g = 0; g < 4; ++g) {
    if (wr == (g >> 1)) {
#pragma unroll
      for (int ii = 0; ii < 2; ++ii) {
        int i = (g & 1) * 2 + ii;
#pragma unroll
        for (int j = 0; j < 4; ++j) {
          int colc = wc * 64 + j * 16 + l16;
#pragma unroll
          for (int q = 0; q < 4; ++q) {
            int lr = ii * 16 + lk * 4 + q;
            Cst[lr * 260 + colc] = acc[i][j][q];
          }
        }
      }
    }
    __syncthreads();
#pragma unroll
    for (int p = 0; p < 4; ++p) {
      int f = tid + p * 512;              // 0..2047
      int row = f >> 6, c4 = (f & 63) * 4;
      int gm = bm + g * 32 + row;
      if (gm < N_NODES) {
        float4 v = *(const float4*)&Cst[row * 260 + c4];
        size_t r = (size_t)gm * NHID + c4;
        float4 o;
        if (MODE == 0) {
          float4 bb = *(const float4*)&bias[c4];
          o.x = fmaxf(v.x + bb.x, 0.f);
          o.y = fmaxf(v.y + bb.y, 0.f);
          o.z = fmaxf(v.z + bb.z, 0.f);
          o.w = fmaxf(v.w + bb.w, 0.f);
          *(float4*)&out1[r] = o;
          *(float4*)&out2[r] = o;
        } else {
          ushort4 sh = *(const ushort4*)&Ah_g[r];   // K == NHID in MODE 1
          ushort4 sl = *(const ushort4*)&Al_g[r];
          float4 hv = *(const float4*)&hin[r];
          float sx = bf16_tof(sh.x) + bf16_tof(sl.x);
          float sy = bf16_tof(sh.y) + bf16_tof(sl.y);
          float sz = bf16_tof(sh.z) + bf16_tof(sl.z);
          float sw = bf16_tof(sh.w) + bf16_tof(sl.w);
          o.x = fmaxf(theta * v.x + omt * sx + hv.x, 0.f);
          o.y = fmaxf(theta * v.y + omt * sy + hv.y, 0.f);
          o.z = fmaxf(theta * v.z + omt * sz + hv.z, 0.f);
          o.w = fmaxf(theta * v.w + omt * sw + hv.w, 0.f);
          *(float4*)&out1[r] = o;
        }
      }
    }
    __syncthreads();
  }
}

// ---------------- head: out = sigmoid(h @ w1 + b1) ----------------
__global__ __launch_bounds__(256)
void k_final(const float* __restrict__ h, const float* __restrict__ w1,
             const float* __restrict__ b1, float* __restrict__ out) {
  __shared__ float ws[NHID * NCLASS];
  int t = threadIdx.x;
  for (int i = t; i < NHID * NCLASS; i += 256) ws[i] = w1[i];
  __syncthreads();
  int node = blockIdx.x * 16 + (t >> 4);
  int c = t & 15;
  if (node >= N_NODES) return;
  float acc = b1[c];
  const float* hr = &h[(size_t)node * NHID];
  for (int k = 0; k < NHID; k += 4) {
    float4 hv = *(const float4*)&hr[k];
    acc += hv.x * ws[(k + 0) * NCLASS + c];
    acc += hv.y * ws[(k + 1) * NCLASS + c];
    acc += hv.z * ws[(k + 2) * NCLASS + c];
    acc += hv.w * ws[(k + 3) * NCLASS + c];
  }
  out[(size_t)node * NCLASS + c] = 1.f / (1.f + __expf(-acc));
}

// ---------------- host ----------------
extern "C" void kernel_launch(void* const* d_in, const int* in_sizes, int n_in,
                              void* d_out, int out_size, void* d_ws, size_t ws_size,
                              hipStream_t stream) {
  const float* x        = (const float*)d_in[0];
  const int*   edge_src = (const int*)d_in[1];
  const int*   edge_dst = (const int*)d_in[2];
  const float* edge_w   = (const float*)d_in[3];
  const float* w0       = (const float*)d_in[4];
  const float* b0       = (const float*)d_in[5];
  const float* conv_w   = (const float*)d_in[6];
  const float* w1       = (const float*)d_in[7];
  const float* b1       = (const float*)d_in[8];
  float* out = (float*)d_out;

  char* ws = (char*)d_ws;
  size_t off = 0;
  auto alloc = [&](size_t bytes) {
    size_t o = off;
    off = (off + bytes + 255) & ~(size_t)255;
    return (void*)(ws + o);
  };
  float* h    = (float*)alloc((size_t)N_NODES * NHID * 4);
  float* h0   = (float*)alloc((size_t)N_NODES * NHID * 4);
  unsigned short* sup_hi = (unsigned short*)alloc((size_t)N_NODES * NHID * 2);
  unsigned short* sup_lo = (unsigned short*)alloc((size_t)N_NODES * NHID * 2);
  int2*  cv  = (int2*)alloc((size_t)N_EDGES * 8);
  int*   rp  = (int*)alloc((size_t)(N_NODES + 1) * 4);
  int*   cnt = (int*)alloc((size_t)N_NODES * 4);
  int*   bs  = (int*)alloc((size_t)NB * 4);
  unsigned short* w0t_hi = (unsigned short*)alloc((size_t)NFEAT * NHID * 2);
  unsigned short* w0t_lo = (unsigned short*)alloc((size_t)NFEAT * NHID * 2);
  unsigned short* cwt_hi = (unsigned short*)alloc((size_t)NLAYERS * NHID * NHID * 2);
  unsigned short* cwt_lo = (unsigned short*)alloc((size_t)NLAYERS * NHID * NHID * 2);
  (void)ws_size;

  // ---- CSR build ----
  (void)hipMemsetAsync(cnt, 0, (size_t)N_NODES * 4, stream);
  k_hist<<<(N_EDGES + 255) / 256, 256, 0, stream>>>(edge_dst, cnt);
  k_blocksum<<<NB, 256, 0, stream>>>(cnt, bs);
  k_scan_top<<<1, 64, 0, stream>>>(bs, rp);
  k_scan_write<<<NB, 256, 0, stream>>>(cnt, bs, rp);
  (void)hipMemsetAsync(cnt, 0, (size_t)N_NODES * 4, stream);
  k_fill<<<(N_EDGES + 255) / 256, 256, 0, stream>>>(edge_src, edge_dst, edge_w, rp,
                                                    cnt, cv);

  // ---- split + transpose weights to bf16 hi/lo [N][K] ----
  k_splitw<<<dim3((NFEAT * NHID + 255) / 256, 1), 256, 0, stream>>>(w0, w0t_hi, w0t_lo, NFEAT);
  k_splitw<<<dim3((NHID * NHID + 255) / 256, NLAYERS), 256, 0, stream>>>(conv_w, cwt_hi, cwt_lo, NHID);

  // ---- h = relu(x@w0 + b0); h0 = h ----
  int gblocks = (N_NODES + 127) / 128;   // 782
  k_gemm2<0><<<gblocks, 512, 0, stream>>>(x, nullptr, nullptr, w0t_hi, w0t_lo,
                                          NFEAT, b0, nullptr, h, h0, 0.f);

  // ---- 8 GCNII layers; even layers quarter-split, odd layers half-split ----
  for (int i = 0; i < NLAYERS; ++i) {
    float theta = logf(0.5f / (float)(i + 1) + 1.0f);
    if ((i & 1) == 0) {
      for (int f0 = 0; f0 < NHID; f0 += 64)
        k_spmm_q<<<(N_NODES + 3) / 4, 256, 0, stream>>>(rp, cv, h, h0,
                                                        sup_hi, sup_lo, f0);
    } else {
      for (int f0 = 0; f0 < NHID; f0 += 128)
        k_spmm_h<<<(N_NODES + 3) / 4, 256, 0, stream>>>(rp, cv, h, h0,
                                                        sup_hi, sup_lo, f0);
    }
    const unsigned short* whi = cwt_hi + (size_t)i * NHID * NHID;
    const unsigned short* wlo = cwt_lo + (size_t)i * NHID * NHID;
    k_gemm2<1><<<gblocks, 512, 0, stream>>>(nullptr, sup_hi, sup_lo, whi, wlo,
                                            NHID, nullptr, h, h, nullptr, theta);
  }

  // ---- head ----
  k_final<<<(N_NODES + 15) / 16, 256, 0, stream>>>(h, w1, b1, out);
}